// Round 22
// baseline (152.613 us; speedup 1.0000x reference)
//
#include <hip/hip_runtime.h>
#include <hip/hip_bf16.h>
#include <stdint.h>
#include <string.h>

#define S_LEN 2048
#define NH    16
#define DH    64
#define D_EMB 1024
#define CSCALE 0.18033688011112042f  // 0.125 * log2(e), folded into Q at QKV epilogue

typedef __attribute__((ext_vector_type(8)))  short short8;
typedef __attribute__((ext_vector_type(4)))  float f32x4;
typedef __attribute__((ext_vector_type(16))) float f32x16;
typedef __attribute__((ext_vector_type(4)))  uint32_t u32x4;

__device__ __forceinline__ unsigned short f2bf(float f) {
  uint32_t u = __builtin_bit_cast(uint32_t, f);
  uint32_t r = (u + 0x7FFFu + ((u >> 16) & 1u)) >> 16;
  return (unsigned short)r;
}

__device__ __forceinline__ uint32_t pkbf(float a, float b) {
  float2 f; f.x = a; f.y = b;
  __hip_bfloat162 h = __float22bfloat162_rn(f);
  uint32_t r;
  memcpy(&r, &h, 4);
  return r;
}

// truncating bf16 pack: D = [b.hi16, a.hi16] -> one v_perm_b32
__device__ __forceinline__ uint32_t pktr(float a, float b) {
  return __builtin_amdgcn_perm(__builtin_bit_cast(uint32_t, b),
                               __builtin_bit_cast(uint32_t, a), 0x07060302u);
}

// raw v_exp_f32 (plain -O3 lowers exp2f to the slow correctly-rounded OCML call)
__device__ __forceinline__ float fexp2(float x) {
#if __has_builtin(__builtin_amdgcn_exp2f)
  return __builtin_amdgcn_exp2f(x);
#else
  float r;
  asm("v_exp_f32 %0, %1\ns_nop 0" : "=v"(r) : "v"(x));
  return r;
#endif
}

__device__ __forceinline__ void gload16(const void* g, void* l) {
  __builtin_amdgcn_global_load_lds(
      (__attribute__((address_space(1))) void*)(g),
      (__attribute__((address_space(3))) void*)(l),
      16, 0, 0);
}

__device__ __forceinline__ f32x16 mfma32(short8 a, short8 b, f32x16 c) {
  return __builtin_amdgcn_mfma_f32_32x32x16_bf16(a, b, c, 0, 0, 0);
}

// ---------------- prep: x->bf16 + both weight transposes in ONE launch ----------------

__global__ __launch_bounds__(256)
void prep(const float* __restrict__ x, unsigned short* __restrict__ xb,
          const float* __restrict__ W_in, unsigned short* __restrict__ Wti,
          const float* __restrict__ W_out, unsigned short* __restrict__ Wto) {
  __shared__ float tsh[64][65];
  const int blk = blockIdx.x;
  const int tid = threadIdx.x;
  if (blk < 8192) {
    const int i = (blk * 256 + tid) * 4;
    float4 v = *(const float4*)&x[i];
    ushort4 o;
    o.x = f2bf(v.x); o.y = f2bf(v.y); o.z = f2bf(v.z); o.w = f2bf(v.w);
    *(ushort4*)&xb[i] = o;
    return;
  }
  const float* in; unsigned short* out; int C; int bid;
  if (blk < 8960) { in = W_in;  out = Wti; C = 3072; bid = blk - 8192; }
  else            { in = W_out; out = Wto; C = 1024; bid = blk - 8960; }
  const int br = (bid & 15) << 6;
  const int bc = (bid >> 4) << 6;
  const int tr = tid >> 4;
  const int tc = (tid & 15) << 2;
#pragma unroll
  for (int i = 0; i < 4; ++i) {
    float4 v = *(const float4*)&in[(size_t)(br + tr + i * 16) * C + bc + tc];
    tsh[tr + i * 16][tc + 0] = v.x;
    tsh[tr + i * 16][tc + 1] = v.y;
    tsh[tr + i * 16][tc + 2] = v.z;
    tsh[tr + i * 16][tc + 3] = v.w;
  }
  __syncthreads();
#pragma unroll
  for (int i = 0; i < 4; ++i) {
    int c = tr + i * 16;
    ushort4 o;
    o.x = f2bf(tsh[tc + 0][c]);
    o.y = f2bf(tsh[tc + 1][c]);
    o.z = f2bf(tsh[tc + 2][c]);
    o.w = f2bf(tsh[tc + 3][c]);
    *(ushort4*)&out[(size_t)(bc + c) * 1024 + br + tc] = o;
  }
}

// ---------------- GEMM (A[M][K] bf16 x Bt[N][K] bf16) ----------------
// FINAL (proven best): m97 structure, 128x128 tile, BK=64, SINGLE-buffered
// 32 KB LDS, (256,3) = 3 blocks/CU. T2 XOR swizzle both-sides -> 0 bank
// conflicts. 845 TF / 61.5 us on QKV. Rejected: dbuf, counted vmcnt, 256^2
// 2-phase & 8-phase, T1 XCD swizzle, 4 blocks/CU (all null/regression here).
// MODE 0 epilogue writes Q/K/V in MFMA-FRAGMENT layout per 64-row kv block:
//   base(bh,kb) = (bh*32+kb)*4096; [frag 0..7][lane 0..63][elem 0..7]
//   Q/K: frag=((s>>5)&1)*4+(d>>4); lane=(s&31)+32*((d>>3)&1); elem=d&7
//   V:   frag=(d>>5)*4+((s>>4)&3); lane=(d&31)+32*((s>>3)&1); elem=s&7

template <int MODE>
__global__ __launch_bounds__(256, 3)
void gemm_bt(const unsigned short* __restrict__ A,
             const unsigned short* __restrict__ Bt,
             const float* __restrict__ bias,
             unsigned short* __restrict__ q_out,
             unsigned short* __restrict__ k_out,
             unsigned short* __restrict__ v_out,
             float* __restrict__ f_out,
             int M, int N, int K) {
  __shared__ __attribute__((aligned(16))) unsigned short As[128 * 64];
  __shared__ __attribute__((aligned(16))) unsigned short Bs[128 * 64];
  const int tid  = threadIdx.x;
  const int lane = tid & 63;
  const int w    = tid >> 6;
  const int grp  = lane >> 4;
  const int lc   = lane & 15;
  const int nbn  = N >> 7;
  const int bm   = blockIdx.x / nbn;
  const int bn   = blockIdx.x % nbn;
  const int wr   = w >> 1, wc = w & 1;

  f32x4 acc[4][4];
#pragma unroll
  for (int m = 0; m < 4; ++m)
#pragma unroll
    for (int n = 0; n < 4; ++n) acc[m][n] = f32x4{0.f, 0.f, 0.f, 0.f};

  const int srow = lane >> 3;                  // 0..7
  const int scol = ((lane & 7) ^ srow) * 8;    // T2: pre-swizzled source col
  const int nkt  = K >> 6;

  for (int kt = 0; kt < nkt; ++kt) {
#pragma unroll
    for (int c = 0; c < 4; ++c) {
      const int rc = w * 32 + c * 8;
      gload16(&A[(size_t)(bm * 128 + rc + srow) * K + kt * 64 + scol],
              (void*)(&As[rc * 64]));
      gload16(&Bt[(size_t)(bn * 128 + rc + srow) * K + kt * 64 + scol],
              (void*)(&Bs[rc * 64]));
    }
    __syncthreads();   // compiler drains vmcnt(0) before s_barrier
#pragma unroll
    for (int kk = 0; kk < 2; ++kk) {
      short8 af[4], bf[4];
#pragma unroll
      for (int m = 0; m < 4; ++m) {
        const int row = wr * 64 + m * 16 + lc;
        const int cb  = ((kk * 4 + grp) ^ (lc & 7)) * 8;
        af[m] = *(const short8*)(&As[row * 64 + cb]);
      }
#pragma unroll
      for (int n = 0; n < 4; ++n) {
        const int row = wc * 64 + n * 16 + lc;
        const int cb  = ((kk * 4 + grp) ^ (lc & 7)) * 8;
        bf[n] = *(const short8*)(&Bs[row * 64 + cb]);
      }
      __builtin_amdgcn_s_setprio(1);
#pragma unroll
      for (int m = 0; m < 4; ++m)
#pragma unroll
        for (int n = 0; n < 4; ++n)
          acc[m][n] = __builtin_amdgcn_mfma_f32_16x16x32_bf16(af[m], bf[n], acc[m][n], 0, 0, 0);
      __builtin_amdgcn_s_setprio(0);
    }
    __syncthreads();   // reads done before next stage overwrites
  }

  const int gm0 = bm * 128 + wr * 64;
  const int gn0 = bn * 128 + wc * 64;
  if (MODE == 0) {
    const int seg = gn0 >> 10;
#pragma unroll
    for (int m = 0; m < 4; ++m) {
#pragma unroll
      for (int n = 0; n < 4; ++n) {
        const int gn = gn0 + n * 16 + lc;
        const float bv = bias[gn];
        const int j = gn & 1023;
        const int h = j >> 6, d = j & 63;
        const int gmb = gm0 + m * 16 + grp * 4;
        const int b = gmb >> 11;
        const size_t bhb = ((size_t)(b * NH + h) * 32 + ((gmb & 2047) >> 6)) * 4096;
        if (seg == 2) {
          const size_t vi = bhb + ((d >> 5) * 4 + m) * 512 +
                            ((d & 31) + (grp >> 1) * 32) * 8 + (grp & 1) * 4;
          uint2 dv;
          dv.x = pkbf(acc[m][n][0] + bv, acc[m][n][1] + bv);
          dv.y = pkbf(acc[m][n][2] + bv, acc[m][n][3] + bv);
          *(uint2*)&v_out[vi] = dv;
        } else {
#pragma unroll
          for (int r = 0; r < 4; ++r) {
            const int s = (gmb + r) & 2047;
            float v = acc[m][n][r] + bv;
            if (seg == 0) v *= CSCALE;   // fold softmax scale into Q
            const size_t idx = bhb + (((s >> 5) & 1) * 4 + (d >> 4)) * 512 +
                               ((s & 31) + ((d >> 3) & 1) * 32) * 8 + (d & 7);
            if (seg == 0) q_out[idx] = f2bf(v); else k_out[idx] = f2bf(v);
          }
        }
      }
    }
  } else {
#pragma unroll
    for (int m = 0; m < 4; ++m) {
#pragma unroll
      for (int n = 0; n < 4; ++n) {
        const int gn = gn0 + n * 16 + lc;
        const float bv = bias[gn];
#pragma unroll
        for (int r = 0; r < 4; ++r) {
          const int gm = gm0 + m * 16 + grp * 4 + r;
          f_out[(size_t)gm * N + gn] = acc[m][n][r] + bv;
        }
      }
    }
  }
}

// ---------------- flash attention v13 (8-wave paired-tile, shared KV stage) ----------------
// Grid 512: block = q-tile PAIR {2k, 2k+1} (waves 0-3 -> heavy 2k+1, waves
// 4-7 -> light 2k; light idles only 2 of ~26 iters via the kvb guard).
// ONE shared K/V stage serves all 8 waves -> staging traffic per unit compute
// HALVED vs per-tile blocks; (512,4) -> 2 blocks/CU = 16 waves/CU (vs 12).
// 3-buffer pipeline, 2 gloads/thread/stage, steady-state wait vmcnt(2) =
// stage issued two iterations earlier. Fixed-max softmax; in-register P.

__global__ __launch_bounds__(512, 4)
void attn_fwd13(const unsigned short* __restrict__ Qp,
                const unsigned short* __restrict__ Kp,
                const unsigned short* __restrict__ Vp,
                unsigned short* __restrict__ Aout) {
  __shared__ __attribute__((aligned(16))) unsigned short Sh[6][4096]; // K=0..2, V=3..5
  const int tid  = threadIdx.x;
  const int lane = tid & 63, w = tid >> 6;       // w = 0..7
  const int q32  = lane & 31;
  const int hi   = lane >> 5;
  const int lof  = lane * 8;
  const int g    = blockIdx.x;
  const int tp   = 7 - (g >> 6);                 // pair 7..0, heavy first
  const int bh   = (((g >> 3) & 7) << 3) | (g & 7);  // bh%8 == XCD
  const int b    = bh >> 4, h = bh & 15;
  const size_t fb = (size_t)bh * 32;             // fragment-block base (4096-units)
  const int wl   = w & 3;
  const int t    = 2 * tp + ((w < 4) ? 1 : 0);   // waves 0-3: heavy tile

#define STAGE(bf_, kb_) do {                                          \
    const size_t sb_ = (fb + (size_t)(kb_)) * 4096 + tid * 8;         \
    gload16(Kp + sb_, (void*)&Sh[bf_][tid * 8]);                      \
    gload16(Vp + sb_, (void*)&Sh[3 + (bf_)][tid * 8]);                \
  } while (0)

  const int qw0 = t * 128 + wl * 32;
  const int qkb = 2 * t + (wl >> 1), qsub = wl & 1;

  short8 qf[4];
#pragma unroll
  for (int s = 0; s < 4; ++s)
    qf[s] = *(const short8*)(Qp + (fb + qkb) * 4096 + (qsub * 4 + s) * 512 + lof);

  f32x16 oa, ob;
#pragma unroll
  for (int rr = 0; rr < 16; ++rr) { oa[rr] = 0.f; ob[rr] = 0.f; }
  float l = 0.f;

  const int nbt = 2 * (2 * tp + 1) + 2;   // heavy tile's iter count, >= 4
  STAGE(0, 0);
  STAGE(1, 1);
  int cur = 0;

#pragma unroll 1
  for (int kb = 0; kb < nbt; ++kb) {
    if (kb + 1 < nbt) {
      asm volatile("s_waitcnt vmcnt(2)" ::: "memory");  // stage(kb) resident
    } else {
      asm volatile("s_waitcnt vmcnt(0)" ::: "memory");  // last: drain all
    }
    __builtin_amdgcn_sched_barrier(0);
    __builtin_amdgcn_s_barrier();
    __builtin_amdgcn_sched_barrier(0);

    const int kvb = kb << 6;
    if (kvb <= qw0 + 31) {
      const unsigned short* kl = &Sh[cur][0];
      const unsigned short* vl = &Sh[3 + cur][0];

      f32x16 c0, c1;
#pragma unroll
      for (int rr = 0; rr < 16; ++rr) { c0[rr] = 0.f; c1[rr] = -1e30f; }
      const bool do1 = (kvb + 32 <= qw0 + 31);
      __builtin_amdgcn_s_setprio(1);
#pragma unroll
      for (int s = 0; s < 4; ++s) {
        short8 kf = *(const short8*)(kl + s * 512 + lof);
        c0 = mfma32(kf, qf[s], c0);
      }
      if (do1) {
#pragma unroll
        for (int rr = 0; rr < 16; ++rr) c1[rr] = 0.f;
#pragma unroll
        for (int s = 0; s < 4; ++s) {
          short8 kf = *(const short8*)(kl + (4 + s) * 512 + lof);
          c1 = mfma32(kf, qf[s], c1);
        }
      }
      __builtin_amdgcn_s_setprio(0);

      if (kvb + 63 > qw0) {  // diagonal block: elementwise causal mask
        const int thr = qw0 + q32 - kvb;
#pragma unroll
        for (int rr = 0; rr < 16; ++rr) {
          const int k0 = (rr & 3) + 8 * (rr >> 2) + 4 * hi;
          if (k0 > thr)      c0[rr] = -1e30f;
          if (k0 + 32 > thr) c1[rr] = -1e30f;
        }
      }

      // fixed-max softmax: P = v_exp_f32(S) (masked -> 0)
#pragma unroll
      for (int rr = 0; rr < 16; ++rr) c0[rr] = fexp2(c0[rr]);
#pragma unroll
      for (int rr = 0; rr < 16; ++rr) c1[rr] = fexp2(c1[rr]);
      float tp2[8];
#pragma unroll
      for (int i = 0; i < 8; ++i)
        tp2[i] = (c0[i] + c0[i + 8]) + (c1[i] + c1[i + 8]);
      l += ((tp2[0] + tp2[1]) + (tp2[2] + tp2[3])) +
           ((tp2[4] + tp2[5]) + (tp2[6] + tp2[7]));

      // P^T B-frags in-register: 4 v_perm pack + 2 permlane32_swap per slice
#pragma unroll
      for (int ks = 0; ks < 4; ++ks) {
        if (ks >= 2 && !do1) break;  // upper-half P is all zero when masked
        uint32_t pA, pB, pC, pD;
        if (ks == 0) {
          pA = pktr(c0[0],  c0[1]);  pB = pktr(c0[2],  c0[3]);
          pC = pktr(c0[4],  c0[5]);  pD = pktr(c0[6],  c0[7]);
        } else if (ks == 1) {
          pA = pktr(c0[8],  c0[9]);  pB = pktr(c0[10], c0[11]);
          pC = pktr(c0[12], c0[13]); pD = pktr(c0[14], c0[15]);
        } else if (ks == 2) {
          pA = pktr(c1[0],  c1[1]);  pB = pktr(c1[2],  c1[3]);
          pC = pktr(c1[4],  c1[5]);  pD = pktr(c1[6],  c1[7]);
        } else {
          pA = pktr(c1[8],  c1[9]);  pB = pktr(c1[10], c1[11]);
          pC = pktr(c1[12], c1[13]); pD = pktr(c1[14], c1[15]);
        }
        auto r0 = __builtin_amdgcn_permlane32_swap(pA, pC, false, false);
        auto r1 = __builtin_amdgcn_permlane32_swap(pB, pD, false, false);
        u32x4 fw; fw[0] = r0[0]; fw[1] = r1[0]; fw[2] = r0[1]; fw[3] = r1[1];
        const short8 frag = __builtin_bit_cast(short8, fw);
        oa = mfma32(*(const short8*)(vl + ks * 512 + lof), frag, oa);
        ob = mfma32(*(const short8*)(vl + (4 + ks) * 512 + lof), frag, ob);
      }
    }

    asm volatile("s_waitcnt lgkmcnt(0)" ::: "memory");
    __builtin_amdgcn_sched_barrier(0);
    __builtin_amdgcn_s_barrier();
    __builtin_amdgcn_sched_barrier(0);
    if (kb + 2 < nbt) {
      const int nx = (cur + 2 >= 3) ? cur - 1 : cur + 2;
      STAGE(nx, kb + 2);
    }
    cur = (cur + 1 == 3) ? 0 : cur + 1;
  }

  // epilogue: combine l across halves, normalize, stage bf16 into dead Sh
  l += __shfl_xor(l, 32);
  const float inv = 1.0f / l;
  unsigned short* ebuf = &Sh[0][0];            // 48 KB free; need 8*4 KB
  unsigned short* prow = ebuf + (w * 32 + q32) * 64;
  const int swz = (q32 & 7) << 3;
#pragma unroll
  for (int gg = 0; gg < 4; ++gg) {
    const int d0 = 8 * gg + 4 * hi;
    uint2 da, db;
    da.x = pkbf(oa[4 * gg] * inv,     oa[4 * gg + 1] * inv);
    da.y = pkbf(oa[4 * gg + 2] * inv, oa[4 * gg + 3] * inv);
    db.x = pkbf(ob[4 * gg] * inv,     ob[4 * gg + 1] * inv);
    db.y = pkbf(ob[4 * gg + 2] * inv, ob[4 * gg + 3] * inv);
    *(uint2*)&prow[d0 ^ swz]        = da;
    *(uint2*)&prow[(d0 + 32) ^ swz] = db;
  }
  asm volatile("s_waitcnt lgkmcnt(0)" ::: "memory");
  __builtin_amdgcn_sched_barrier(0);
  const int er = lane >> 1, eh = lane & 1;
  const int rswz = (er & 7) << 3;
  const unsigned short* lr = ebuf + (w * 32 + er) * 64;
  unsigned short* op = Aout + ((size_t)(b * S_LEN + qw0 + er)) * D_EMB + h * DH + eh * 32;
#pragma unroll
  for (int jj = 0; jj < 4; ++jj) {
    short8 ov = *(const short8*)&lr[(eh * 32 + jj * 8) ^ rswz];
    *(short8*)(op + jj * 8) = ov;
  }
#undef STAGE
}

// ---------------- launcher ----------------

extern "C" void kernel_launch(void* const* d_in, const int* in_sizes, int n_in,
                              void* d_out, int out_size, void* d_ws, size_t ws_size,
                              hipStream_t stream) {
  const float* x     = (const float*)d_in[0];
  const float* W_in  = (const float*)d_in[1];
  const float* b_in  = (const float*)d_in[2];
  const float* W_out = (const float*)d_in[3];
  const float* b_out = (const float*)d_in[4];

  char* ws = (char*)d_ws;
  unsigned short* xb  = (unsigned short*)(ws);              // 16 MB: x bf16, later attn_out
  unsigned short* Wti = (unsigned short*)(ws + 16777216);   // 6 MB: W_in^T bf16 [3072][1024]
  unsigned short* Wto = (unsigned short*)(ws + 23068672);   // 2 MB: W_out^T bf16 [1024][1024]
  unsigned short* Qb  = (unsigned short*)(ws + 25165824);   // 16 MB fragment layout
  unsigned short* Kb  = (unsigned short*)(ws + 41943040);   // 16 MB fragment layout
  unsigned short* Vb  = (unsigned short*)(ws + 58720256);   // 16 MB fragment layout
  float* out = (float*)d_out;

  // converters fused into one launch: cvt x + W_in^T + W_out^T
  prep<<<9216, 256, 0, stream>>>(x, xb, W_in, Wti, W_out, Wto);

  // QKV projection: M=8192, N=3072, K=1024 (Q scaled by CSCALE in epilogue)
  gemm_bt<0><<<64 * 24, 256, 0, stream>>>(xb, Wti, b_in, Qb, Kb, Vb, nullptr,
                                          8192, 3072, 1024);
  // causal flash attention: 512 blocks, paired tiles {2k,2k+1}, shared stage
  attn_fwd13<<<512, 512, 0, stream>>>(Qb, Kb, Vb, xb);
  // output projection: M=8192, N=1024, K=1024 -> fp32 + b_out
  gemm_bt<1><<<64 * 8, 256, 0, stream>>>(xb, Wto, b_out, nullptr, nullptr, nullptr, out,
                                         8192, 1024, 1024);
}

// Round 23
// 149.959 us; speedup vs baseline: 1.0177x; 1.0177x over previous
//
#include <hip/hip_runtime.h>
#include <hip/hip_bf16.h>
#include <stdint.h>
#include <string.h>

#define S_LEN 2048
#define NH    16
#define DH    64
#define D_EMB 1024
#define CSCALE 0.18033688011112042f  // 0.125 * log2(e), folded into Q at QKV epilogue

typedef __attribute__((ext_vector_type(8)))  short short8;
typedef __attribute__((ext_vector_type(4)))  float f32x4;
typedef __attribute__((ext_vector_type(16))) float f32x16;
typedef __attribute__((ext_vector_type(4)))  uint32_t u32x4;

__device__ __forceinline__ unsigned short f2bf(float f) {
  uint32_t u = __builtin_bit_cast(uint32_t, f);
  uint32_t r = (u + 0x7FFFu + ((u >> 16) & 1u)) >> 16;
  return (unsigned short)r;
}

__device__ __forceinline__ uint32_t pkbf(float a, float b) {
  float2 f; f.x = a; f.y = b;
  __hip_bfloat162 h = __float22bfloat162_rn(f);
  uint32_t r;
  memcpy(&r, &h, 4);
  return r;
}

// truncating bf16 pack: D = [b.hi16, a.hi16] -> one v_perm_b32
__device__ __forceinline__ uint32_t pktr(float a, float b) {
  return __builtin_amdgcn_perm(__builtin_bit_cast(uint32_t, b),
                               __builtin_bit_cast(uint32_t, a), 0x07060302u);
}

// raw v_exp_f32 (plain -O3 lowers exp2f to the slow correctly-rounded OCML call)
__device__ __forceinline__ float fexp2(float x) {
#if __has_builtin(__builtin_amdgcn_exp2f)
  return __builtin_amdgcn_exp2f(x);
#else
  float r;
  asm("v_exp_f32 %0, %1\ns_nop 0" : "=v"(r) : "v"(x));
  return r;
#endif
}

__device__ __forceinline__ void gload16(const void* g, void* l) {
  __builtin_amdgcn_global_load_lds(
      (__attribute__((address_space(1))) void*)(g),
      (__attribute__((address_space(3))) void*)(l),
      16, 0, 0);
}

__device__ __forceinline__ f32x16 mfma32(short8 a, short8 b, f32x16 c) {
  return __builtin_amdgcn_mfma_f32_32x32x16_bf16(a, b, c, 0, 0, 0);
}

// ---------------- prep: x->bf16 + both weight transposes in ONE launch ----------------

__global__ __launch_bounds__(256)
void prep(const float* __restrict__ x, unsigned short* __restrict__ xb,
          const float* __restrict__ W_in, unsigned short* __restrict__ Wti,
          const float* __restrict__ W_out, unsigned short* __restrict__ Wto) {
  __shared__ float tsh[64][65];
  const int blk = blockIdx.x;
  const int tid = threadIdx.x;
  if (blk < 8192) {
    const int i = (blk * 256 + tid) * 4;
    float4 v = *(const float4*)&x[i];
    ushort4 o;
    o.x = f2bf(v.x); o.y = f2bf(v.y); o.z = f2bf(v.z); o.w = f2bf(v.w);
    *(ushort4*)&xb[i] = o;
    return;
  }
  const float* in; unsigned short* out; int C; int bid;
  if (blk < 8960) { in = W_in;  out = Wti; C = 3072; bid = blk - 8192; }
  else            { in = W_out; out = Wto; C = 1024; bid = blk - 8960; }
  const int br = (bid & 15) << 6;
  const int bc = (bid >> 4) << 6;
  const int tr = tid >> 4;
  const int tc = (tid & 15) << 2;
#pragma unroll
  for (int i = 0; i < 4; ++i) {
    float4 v = *(const float4*)&in[(size_t)(br + tr + i * 16) * C + bc + tc];
    tsh[tr + i * 16][tc + 0] = v.x;
    tsh[tr + i * 16][tc + 1] = v.y;
    tsh[tr + i * 16][tc + 2] = v.z;
    tsh[tr + i * 16][tc + 3] = v.w;
  }
  __syncthreads();
#pragma unroll
  for (int i = 0; i < 4; ++i) {
    int c = tr + i * 16;
    ushort4 o;
    o.x = f2bf(tsh[tc + 0][c]);
    o.y = f2bf(tsh[tc + 1][c]);
    o.z = f2bf(tsh[tc + 2][c]);
    o.w = f2bf(tsh[tc + 3][c]);
    *(ushort4*)&out[(size_t)(bc + c) * 1024 + br + tc] = o;
  }
}

// ---------------- GEMM (A[M][K] bf16 x Bt[N][K] bf16) ----------------
// FINAL (proven best, 149.8 us total): m97 structure, 128x128 tile, BK=64,
// SINGLE-buffered 32 KB LDS, (256,3) = 3 blocks/CU. T2 XOR swizzle
// both-sides -> 0 bank conflicts. 845 TF / 61.5 us on QKV.
// Probed and rejected this session: explicit dbuf, counted vmcnt, 256^2
// 2-phase & 8-phase schedules, T1 XCD swizzle (FETCH -20% but not
// memory-bound), 4 blocks/CU occupancy — all null or regressions at K=1024.
// MODE 0 epilogue writes Q/K/V in MFMA-FRAGMENT layout per 64-row kv block:
//   base(bh,kb) = (bh*32+kb)*4096; [frag 0..7][lane 0..63][elem 0..7]
//   Q/K: frag=((s>>5)&1)*4+(d>>4); lane=(s&31)+32*((d>>3)&1); elem=d&7
//   V:   frag=(d>>5)*4+((s>>4)&3); lane=(d&31)+32*((s>>3)&1); elem=s&7

template <int MODE>
__global__ __launch_bounds__(256, 3)
void gemm_bt(const unsigned short* __restrict__ A,
             const unsigned short* __restrict__ Bt,
             const float* __restrict__ bias,
             unsigned short* __restrict__ q_out,
             unsigned short* __restrict__ k_out,
             unsigned short* __restrict__ v_out,
             float* __restrict__ f_out,
             int M, int N, int K) {
  __shared__ __attribute__((aligned(16))) unsigned short As[128 * 64];
  __shared__ __attribute__((aligned(16))) unsigned short Bs[128 * 64];
  const int tid  = threadIdx.x;
  const int lane = tid & 63;
  const int w    = tid >> 6;
  const int grp  = lane >> 4;
  const int lc   = lane & 15;
  const int nbn  = N >> 7;
  const int bm   = blockIdx.x / nbn;
  const int bn   = blockIdx.x % nbn;
  const int wr   = w >> 1, wc = w & 1;

  f32x4 acc[4][4];
#pragma unroll
  for (int m = 0; m < 4; ++m)
#pragma unroll
    for (int n = 0; n < 4; ++n) acc[m][n] = f32x4{0.f, 0.f, 0.f, 0.f};

  const int srow = lane >> 3;                  // 0..7
  const int scol = ((lane & 7) ^ srow) * 8;    // T2: pre-swizzled source col
  const int nkt  = K >> 6;

  for (int kt = 0; kt < nkt; ++kt) {
#pragma unroll
    for (int c = 0; c < 4; ++c) {
      const int rc = w * 32 + c * 8;
      gload16(&A[(size_t)(bm * 128 + rc + srow) * K + kt * 64 + scol],
              (void*)(&As[rc * 64]));
      gload16(&Bt[(size_t)(bn * 128 + rc + srow) * K + kt * 64 + scol],
              (void*)(&Bs[rc * 64]));
    }
    __syncthreads();   // compiler drains vmcnt(0) before s_barrier
#pragma unroll
    for (int kk = 0; kk < 2; ++kk) {
      short8 af[4], bf[4];
#pragma unroll
      for (int m = 0; m < 4; ++m) {
        const int row = wr * 64 + m * 16 + lc;
        const int cb  = ((kk * 4 + grp) ^ (lc & 7)) * 8;
        af[m] = *(const short8*)(&As[row * 64 + cb]);
      }
#pragma unroll
      for (int n = 0; n < 4; ++n) {
        const int row = wc * 64 + n * 16 + lc;
        const int cb  = ((kk * 4 + grp) ^ (lc & 7)) * 8;
        bf[n] = *(const short8*)(&Bs[row * 64 + cb]);
      }
      __builtin_amdgcn_s_setprio(1);
#pragma unroll
      for (int m = 0; m < 4; ++m)
#pragma unroll
        for (int n = 0; n < 4; ++n)
          acc[m][n] = __builtin_amdgcn_mfma_f32_16x16x32_bf16(af[m], bf[n], acc[m][n], 0, 0, 0);
      __builtin_amdgcn_s_setprio(0);
    }
    __syncthreads();   // reads done before next stage overwrites
  }

  const int gm0 = bm * 128 + wr * 64;
  const int gn0 = bn * 128 + wc * 64;
  if (MODE == 0) {
    const int seg = gn0 >> 10;
#pragma unroll
    for (int m = 0; m < 4; ++m) {
#pragma unroll
      for (int n = 0; n < 4; ++n) {
        const int gn = gn0 + n * 16 + lc;
        const float bv = bias[gn];
        const int j = gn & 1023;
        const int h = j >> 6, d = j & 63;
        const int gmb = gm0 + m * 16 + grp * 4;
        const int b = gmb >> 11;
        const size_t bhb = ((size_t)(b * NH + h) * 32 + ((gmb & 2047) >> 6)) * 4096;
        if (seg == 2) {
          const size_t vi = bhb + ((d >> 5) * 4 + m) * 512 +
                            ((d & 31) + (grp >> 1) * 32) * 8 + (grp & 1) * 4;
          uint2 dv;
          dv.x = pkbf(acc[m][n][0] + bv, acc[m][n][1] + bv);
          dv.y = pkbf(acc[m][n][2] + bv, acc[m][n][3] + bv);
          *(uint2*)&v_out[vi] = dv;
        } else {
#pragma unroll
          for (int r = 0; r < 4; ++r) {
            const int s = (gmb + r) & 2047;
            float v = acc[m][n][r] + bv;
            if (seg == 0) v *= CSCALE;   // fold softmax scale into Q
            const size_t idx = bhb + (((s >> 5) & 1) * 4 + (d >> 4)) * 512 +
                               ((s & 31) + ((d >> 3) & 1) * 32) * 8 + (d & 7);
            if (seg == 0) q_out[idx] = f2bf(v); else k_out[idx] = f2bf(v);
          }
        }
      }
    }
  } else {
#pragma unroll
    for (int m = 0; m < 4; ++m) {
#pragma unroll
      for (int n = 0; n < 4; ++n) {
        const int gn = gn0 + n * 16 + lc;
        const float bv = bias[gn];
#pragma unroll
        for (int r = 0; r < 4; ++r) {
          const int gm = gm0 + m * 16 + grp * 4 + r;
          f_out[(size_t)gm * N + gn] = acc[m][n][r] + bv;
        }
      }
    }
  }
}

// ---------------- flash attention v10 (3-buffer KV pipeline, counted vmcnt) ----------------
// FINAL (proven best): Q,K,V in fragment layout. Grid 1024, one 128-row q
// tile per block, heavy first, bh%8 == XCD. Fixed-max softmax
// (P = v_exp_f32(s), exact by shift invariance); P->PV B-frags in-register
// via v_perm pack + 2x permlane32_swap (no LDS roundtrip, no bank conflicts).
// 3 LDS buffers; STAGE(kb+2) after tail barrier; wait vmcnt(4) = loads from
// TWO iterations (~1500 cy) earlier. Probed and rejected: 2-buf 4 blocks/CU,
// direct-global zero-barrier, 8-wave paired-tile shared stage.

__global__ __launch_bounds__(256, 3)
void attn_fwd10(const unsigned short* __restrict__ Qp,
                const unsigned short* __restrict__ Kp,
                const unsigned short* __restrict__ Vp,
                unsigned short* __restrict__ Aout) {
  __shared__ __attribute__((aligned(16))) unsigned short Ks[3][4096];
  __shared__ __attribute__((aligned(16))) unsigned short Vs[3][4096];
  const int tid  = threadIdx.x;
  const int lane = tid & 63, w = tid >> 6;
  const int q32  = lane & 31;
  const int hi   = lane >> 5;
  const int lof  = lane * 8;
  const int g    = blockIdx.x;
  const int t    = 15 - (g >> 6);            // tile 15..0, heavy first
  const int bh   = (((g >> 3) & 7) << 3) | (g & 7);  // bh%8 == XCD
  const int b    = bh >> 4, h = bh & 15;
  const size_t fb = (size_t)bh * 32;         // fragment-block base (4096-units)

#define STAGE(bf_, kb_) do {                                          \
    const size_t sb_ = (fb + (size_t)(kb_)) * 4096 + tid * 8;         \
    gload16(Kp + sb_,        (void*)&Ks[bf_][tid * 8]);               \
    gload16(Kp + sb_ + 2048, (void*)&Ks[bf_][2048 + tid * 8]);        \
    gload16(Vp + sb_,        (void*)&Vs[bf_][tid * 8]);               \
    gload16(Vp + sb_ + 2048, (void*)&Vs[bf_][2048 + tid * 8]);        \
  } while (0)

  const int qw0 = t * 128 + w * 32;
  const int qkb = 2 * t + (w >> 1), qsub = w & 1;

  short8 qf[4];
#pragma unroll
  for (int s = 0; s < 4; ++s)
    qf[s] = *(const short8*)(Qp + (fb + qkb) * 4096 + (qsub * 4 + s) * 512 + lof);

  f32x16 oa, ob;
#pragma unroll
  for (int rr = 0; rr < 16; ++rr) { oa[rr] = 0.f; ob[rr] = 0.f; }
  float l = 0.f;

  const int nbt = 2 * t + 2;   // >= 2 always
  STAGE(0, 0);
  STAGE(1, 1);
  int cur = 0;

#pragma unroll 1
  for (int kb = 0; kb < nbt; ++kb) {
    if (kb + 1 < nbt) {
      asm volatile("s_waitcnt vmcnt(4)" ::: "memory");  // stage(kb) resident
    } else {
      asm volatile("s_waitcnt vmcnt(0)" ::: "memory");  // last: drain all
    }
    __builtin_amdgcn_sched_barrier(0);
    __builtin_amdgcn_s_barrier();
    __builtin_amdgcn_sched_barrier(0);

    const int kvb = kb << 6;
    if (kvb <= qw0 + 31) {
      const unsigned short* kl = &Ks[cur][0];
      const unsigned short* vl = &Vs[cur][0];

      f32x16 c0, c1;
#pragma unroll
      for (int rr = 0; rr < 16; ++rr) { c0[rr] = 0.f; c1[rr] = -1e30f; }
      const bool do1 = (kvb + 32 <= qw0 + 31);
      __builtin_amdgcn_s_setprio(1);
#pragma unroll
      for (int s = 0; s < 4; ++s) {
        short8 kf = *(const short8*)(kl + s * 512 + lof);
        c0 = mfma32(kf, qf[s], c0);
      }
      if (do1) {
#pragma unroll
        for (int rr = 0; rr < 16; ++rr) c1[rr] = 0.f;
#pragma unroll
        for (int s = 0; s < 4; ++s) {
          short8 kf = *(const short8*)(kl + (4 + s) * 512 + lof);
          c1 = mfma32(kf, qf[s], c1);
        }
      }
      __builtin_amdgcn_s_setprio(0);

      if (kvb + 63 > qw0) {  // diagonal block: elementwise causal mask
        const int thr = qw0 + q32 - kvb;
#pragma unroll
        for (int rr = 0; rr < 16; ++rr) {
          const int k0 = (rr & 3) + 8 * (rr >> 2) + 4 * hi;
          if (k0 > thr)      c0[rr] = -1e30f;
          if (k0 + 32 > thr) c1[rr] = -1e30f;
        }
      }

      // fixed-max softmax: P = v_exp_f32(S) (masked -> 0)
#pragma unroll
      for (int rr = 0; rr < 16; ++rr) c0[rr] = fexp2(c0[rr]);
#pragma unroll
      for (int rr = 0; rr < 16; ++rr) c1[rr] = fexp2(c1[rr]);
      float tp[8];
#pragma unroll
      for (int i = 0; i < 8; ++i)
        tp[i] = (c0[i] + c0[i + 8]) + (c1[i] + c1[i + 8]);
      l += ((tp[0] + tp[1]) + (tp[2] + tp[3])) +
           ((tp[4] + tp[5]) + (tp[6] + tp[7]));

      // P^T B-frags in-register: 4 v_perm pack + 2 permlane32_swap per slice
#pragma unroll
      for (int ks = 0; ks < 4; ++ks) {
        if (ks >= 2 && !do1) break;  // upper-half P is all zero when masked
        uint32_t pA, pB, pC, pD;
        if (ks == 0) {
          pA = pktr(c0[0],  c0[1]);  pB = pktr(c0[2],  c0[3]);
          pC = pktr(c0[4],  c0[5]);  pD = pktr(c0[6],  c0[7]);
        } else if (ks == 1) {
          pA = pktr(c0[8],  c0[9]);  pB = pktr(c0[10], c0[11]);
          pC = pktr(c0[12], c0[13]); pD = pktr(c0[14], c0[15]);
        } else if (ks == 2) {
          pA = pktr(c1[0],  c1[1]);  pB = pktr(c1[2],  c1[3]);
          pC = pktr(c1[4],  c1[5]);  pD = pktr(c1[6],  c1[7]);
        } else {
          pA = pktr(c1[8],  c1[9]);  pB = pktr(c1[10], c1[11]);
          pC = pktr(c1[12], c1[13]); pD = pktr(c1[14], c1[15]);
        }
        auto r0 = __builtin_amdgcn_permlane32_swap(pA, pC, false, false);
        auto r1 = __builtin_amdgcn_permlane32_swap(pB, pD, false, false);
        u32x4 fw; fw[0] = r0[0]; fw[1] = r1[0]; fw[2] = r0[1]; fw[3] = r1[1];
        const short8 frag = __builtin_bit_cast(short8, fw);
        oa = mfma32(*(const short8*)(vl + ks * 512 + lof), frag, oa);
        ob = mfma32(*(const short8*)(vl + (4 + ks) * 512 + lof), frag, ob);
      }
    }

    asm volatile("s_waitcnt lgkmcnt(0)" ::: "memory");
    __builtin_amdgcn_sched_barrier(0);
    __builtin_amdgcn_s_barrier();
    __builtin_amdgcn_sched_barrier(0);
    if (kb + 2 < nbt) {
      const int nx = (cur + 2 >= 3) ? cur - 1 : cur + 2;
      STAGE(nx, kb + 2);
    }
    cur = (cur + 1 == 3) ? 0 : cur + 1;
  }

  // epilogue: combine l across halves, normalize, stage bf16 into dead Ks
  l += __shfl_xor(l, 32);
  const float inv = 1.0f / l;
  unsigned short* ebuf = (unsigned short*)Ks;        // free after loop
  unsigned short* prow = ebuf + (w * 32 + q32) * 64;
  const int swz = (q32 & 7) << 3;
#pragma unroll
  for (int gg = 0; gg < 4; ++gg) {
    const int d0 = 8 * gg + 4 * hi;
    uint2 da, db;
    da.x = pkbf(oa[4 * gg] * inv,     oa[4 * gg + 1] * inv);
    da.y = pkbf(oa[4 * gg + 2] * inv, oa[4 * gg + 3] * inv);
    db.x = pkbf(ob[4 * gg] * inv,     ob[4 * gg + 1] * inv);
    db.y = pkbf(ob[4 * gg + 2] * inv, ob[4 * gg + 3] * inv);
    *(uint2*)&prow[d0 ^ swz]        = da;
    *(uint2*)&prow[(d0 + 32) ^ swz] = db;
  }
  asm volatile("s_waitcnt lgkmcnt(0)" ::: "memory");
  __builtin_amdgcn_sched_barrier(0);
  const int er = lane >> 1, eh = lane & 1;
  const int rswz = (er & 7) << 3;
  const unsigned short* lr = ebuf + (w * 32 + er) * 64;
  unsigned short* op = Aout + ((size_t)(b * S_LEN + qw0 + er)) * D_EMB + h * DH + eh * 32;
#pragma unroll
  for (int jj = 0; jj < 4; ++jj) {
    short8 ov = *(const short8*)&lr[(eh * 32 + jj * 8) ^ rswz];
    *(short8*)(op + jj * 8) = ov;
  }
#undef STAGE
}

// ---------------- launcher ----------------

extern "C" void kernel_launch(void* const* d_in, const int* in_sizes, int n_in,
                              void* d_out, int out_size, void* d_ws, size_t ws_size,
                              hipStream_t stream) {
  const float* x     = (const float*)d_in[0];
  const float* W_in  = (const float*)d_in[1];
  const float* b_in  = (const float*)d_in[2];
  const float* W_out = (const float*)d_in[3];
  const float* b_out = (const float*)d_in[4];

  char* ws = (char*)d_ws;
  unsigned short* xb  = (unsigned short*)(ws);              // 16 MB: x bf16, later attn_out
  unsigned short* Wti = (unsigned short*)(ws + 16777216);   // 6 MB: W_in^T bf16 [3072][1024]
  unsigned short* Wto = (unsigned short*)(ws + 23068672);   // 2 MB: W_out^T bf16 [1024][1024]
  unsigned short* Qb  = (unsigned short*)(ws + 25165824);   // 16 MB fragment layout
  unsigned short* Kb  = (unsigned short*)(ws + 41943040);   // 16 MB fragment layout
  unsigned short* Vb  = (unsigned short*)(ws + 58720256);   // 16 MB fragment layout
  float* out = (float*)d_out;

  // converters fused into one launch: cvt x + W_in^T + W_out^T
  prep<<<9216, 256, 0, stream>>>(x, xb, W_in, Wti, W_out, Wto);

  // QKV projection: M=8192, N=3072, K=1024 (Q scaled by CSCALE in epilogue)
  gemm_bt<0><<<64 * 24, 256, 0, stream>>>(xb, Wti, b_in, Qb, Kb, Vb, nullptr,
                                          8192, 3072, 1024);
  // causal flash attention: 1024 blocks, one q-tile each, heavy-first
  attn_fwd10<<<1024, 256, 0, stream>>>(Qb, Kb, Vb, xb);
  // output projection: M=8192, N=1024, K=1024 -> fp32 + b_out
  gemm_bt<1><<<64 * 8, 256, 0, stream>>>(xb, Wto, b_out, nullptr, nullptr, nullptr, out,
                                         8192, 1024, 1024);
}